// Round 3
// baseline (241.391 us; speedup 1.0000x reference)
//
#include <hip/hip_runtime.h>
#include <hip/hip_bf16.h>
#include <stdint.h>

#define T_DIM 2048
#define N_DIM 512
#define DV_DIM 128
#define NH 16          // B*H

typedef __bf16 bf16x8 __attribute__((ext_vector_type(8)));
typedef float f32x4 __attribute__((ext_vector_type(4)));
typedef float f32x2 __attribute__((ext_vector_type(2)));
typedef unsigned int u32x2 __attribute__((ext_vector_type(2)));
typedef unsigned int u32x4 __attribute__((ext_vector_type(4)));

__device__ __forceinline__ unsigned bf16rne(float x) {
  unsigned u = __builtin_bit_cast(unsigned, x);
  return (u + 0x7FFFu + ((u >> 16) & 1u)) >> 16;
}

__device__ __forceinline__ void load_lds16(const void* g, void* l) {
  __builtin_amdgcn_global_load_lds((const __attribute__((address_space(1))) void*)g,
                                   (__attribute__((address_space(3))) void*)l, 16, 0, 0);
}

// ---------------- RoPE: Q fp32 -> QR bf16  [bh][t][n] ----------------
__global__ void rope_kernel(const float* __restrict__ Q, const float* __restrict__ freqs,
                            unsigned int* __restrict__ qrOut) {
  const int total = NH * T_DIM * (N_DIM / 2);  // pairs
  for (int p = blockIdx.x * blockDim.x + threadIdx.x; p < total;
       p += gridDim.x * blockDim.x) {
    int n2 = p & 255;            // N/2 = 256
    int t = (p >> 8) & 2047;
    float f = freqs[2 * n2];
    f32x2 q = *(const f32x2*)(Q + 2 * (size_t)p);
    float ph = (float)t * f;
    ph = ph - floorf(ph);                 // revolutions in [0,1)
    float sn = __builtin_amdgcn_sinf(ph);
    float cn = __builtin_amdgcn_cosf(ph);
    float o0 = q.x * cn - q.y * sn;
    float o1 = q.y * cn + q.x * sn;
    qrOut[p] = bf16rne(o0) | (bf16rne(o1) << 16);
  }
}

// ---------------- V -> blocked VT bf16: vtb[bh][t/16][d][t%16] ----------------
__global__ void vtrans_kernel(const float* __restrict__ V, unsigned short* __restrict__ vtb) {
  __shared__ unsigned short tile[64][65];
  int blk = blockIdx.x;
  int bh = blk >> 6;
  int tt = (blk >> 1) & 31;  // t-tile (64 rows)
  int td = blk & 1;          // d-half (64)
  int t0 = tt * 64, d0 = td * 64;
  const float* src = V + ((size_t)bh * T_DIM + t0) * DV_DIM + d0;
  int tid = threadIdx.x;
#pragma unroll
  for (int it = 0; it < 16; ++it) {
    int sl = it * 256 + tid;
    int r = sl >> 6, c = sl & 63;   // r = t-local, c = d-local
    tile[r][c] = (unsigned short)bf16rne(src[r * DV_DIM + c]);
  }
  __syncthreads();
  int jl = tid >> 6;       // 0..3
  int dl = tid & 63;       // 0..63
  unsigned short tmp[16];
#pragma unroll
  for (int k = 0; k < 16; ++k) tmp[k] = tile[jl * 16 + k][dl];
  unsigned short* dst = vtb + (size_t)bh * (128 * DV_DIM * 16)
                        + (size_t)(tt * 4 + jl) * (DV_DIM * 16)
                        + (size_t)(d0 + dl) * 16;
  *(u32x4*)(dst) = *(u32x4*)(tmp);
  *(u32x4*)(dst + 8) = *(u32x4*)(tmp + 8);
}

// ---------------- fused masked attention ----------------
// 1024 wgs x 128 thr (2 waves). wg = (head, pair ph, jpar 0..3), bid%8 pins
// head to XCD. Segments: block 31-ph (32-ph steps) then block ph (ph+1 steps)
// -> uniform 33 steps per wg. Per step: stage 16-row K-block (dbuf), swapped
// QK^T (S rows = s-cols -> b64 S stores), PV every 2 steps. O via atomicAdd.
__global__ __launch_bounds__(128, 2)
void attn_kernel(const unsigned short* __restrict__ qr,
                 const unsigned short* __restrict__ vtb,
                 float* __restrict__ out) {
  __shared__ unsigned short k_lds[2][16 * 16 * 32];  // [buf][ks][row16][32 bf16]
  __shared__ unsigned short s_lds[4][16 * 32];       // [w*2+tile][t16][32 s]

  const int tid = threadIdx.x;
  const int w = tid >> 6;
  const int lane = tid & 63;
  const int lh = lane & 15;
  const int lg = lane >> 4;

  const int bid = blockIdx.x;
  const int x = bid & 7;
  const int k = bid >> 3;                 // 0..127
  const int head = x + 8 * (k >> 6);
  const int kk = k & 63;
  const int ph = kk >> 2;                 // pair 0..15
  const int jpar = kk & 3;

  const int n0 = 32 - ph;                 // steps in segment 0 (block 31-ph)
  const int n1 = ph + 1;                  // steps in segment 1 (block ph)
  const int R0 = 31 - ph, R1 = ph;

  const unsigned short* qr_h = qr + (size_t)head * (T_DIM * N_DIM);
  const unsigned short* vtb_h = vtb + (size_t)head * (128 * DV_DIM * 16);

  u32x4 qA[16], qB[16];                   // Q B-frags: tiles +16w and +32+16w
  {
    const unsigned short* pa = qr_h + (size_t)(R0 * 64 + 16 * w + lh) * N_DIM + lg * 8;
    const unsigned short* pb = pa + 32 * N_DIM;
#pragma unroll
    for (int ks = 0; ks < 16; ++ks) {
      qA[ks] = *(const u32x4*)(pa + ks * 32);
      qB[ks] = *(const u32x4*)(pb + ks * 32);
    }
  }

  const f32x4 fzero = {0.f, 0.f, 0.f, 0.f};
  f32x4 oA[8], oB[8];
#pragma unroll
  for (int d = 0; d < 8; ++d) { oA[d] = fzero; oB[d] = fzero; }

  u32x4 vfr[8];
  float* const out_h = out + (size_t)head * T_DIM * DV_DIM;

  // prologue: stage first block (jl = jpar) into buf 0
  {
    const char* base = (const char*)qr_h + (size_t)jpar * 16384;
#pragma unroll
    for (int it = 0; it < 8; ++it) {
      int slot = it * 128 + tid;
      int off = ((slot >> 2) & 15) * 1024 + (slot >> 6) * 64 + (slot & 3) * 16;
      load_lds16(base + off, (char*)k_lds + slot * 16);
    }
  }
  __syncthreads();

  for (int t = 0; t < 33; ++t) {
    const bool seg1 = (t >= n0);
    const int sseg = seg1 ? (t - n0) : t;
    const int REG = seg1 ? R1 : R0;
    const int jl = jpar + 4 * sseg;
    const int buf = t & 1;
    const int par = sseg & 1;
    const bool last = seg1 ? (sseg == n1 - 1) : (sseg == n0 - 1);
    const bool dummy = (par == 0) && last;

    // stage next block
    if (t + 1 < 33) {
      const int tn = t + 1;
      const int jln = (tn >= n0) ? jpar + 4 * (tn - n0) : jpar + 4 * tn;
      const char* base = (const char*)qr_h + (size_t)jln * 16384;
      char* dst = (char*)k_lds + (buf ^ 1) * 16384;
#pragma unroll
      for (int it = 0; it < 8; ++it) {
        int slot = it * 128 + tid;
        int off = ((slot >> 2) & 15) * 1024 + (slot >> 6) * 64 + (slot & 3) * 16;
        load_lds16(base + off, dst + slot * 16);
      }
    }

    // segment boundary: flush O for R0, reload Q for R1, zero O
    if (t == n0) {
#pragma unroll
      for (int df = 0; df < 8; ++df) {
        int dfi = (df + 2 * jpar) & 7;
#pragma unroll
        for (int r = 0; r < 4; ++r) {
          atomicAdd(out_h + (size_t)(R0 * 64 + 16 * w + 4 * lg + r) * DV_DIM + dfi * 16 + lh, oA[dfi][r]);
          atomicAdd(out_h + (size_t)(R0 * 64 + 32 + 16 * w + 4 * lg + r) * DV_DIM + dfi * 16 + lh, oB[dfi][r]);
        }
      }
      const unsigned short* pa = qr_h + (size_t)(R1 * 64 + 16 * w + lh) * N_DIM + lg * 8;
      const unsigned short* pb = pa + 32 * N_DIM;
#pragma unroll
      for (int ks = 0; ks < 16; ++ks) {
        qA[ks] = *(const u32x4*)(pa + ks * 32);
        qB[ks] = *(const u32x4*)(pb + ks * 32);
      }
#pragma unroll
      for (int d = 0; d < 8; ++d) { oA[d] = fzero; oB[d] = fzero; }
    }

    // V fragments for the s-pair (jl, jl+4)
    if (par == 0) {
      const int blkB = (jl + 4 <= 127) ? (jl + 4) : jl;
      const int sel = (lg >> 1) ? blkB : jl;
      const unsigned short* vb = vtb_h + (size_t)sel * (DV_DIM * 16) + (lg & 1) * 8;
#pragma unroll
      for (int df = 0; df < 8; ++df)
        vfr[df] = *(const u32x4*)(vb + (df * 16 + lh) * 16);
    }

    // ---- QK^T swapped: S[m=s][n=t] = K·Q^T ----
    f32x4 sA = fzero, sB = fzero;
    const int kbase = buf * 16384 + lh * 64 + lg * 16;  // bytes: A-frag s-row lh
#pragma unroll
    for (int ks = 0; ks < 16; ++ks) {
      bf16x8 kf = *(const bf16x8*)((const char*)k_lds + kbase + ks * 1024);
      sA = __builtin_amdgcn_mfma_f32_16x16x32_bf16(kf, __builtin_bit_cast(bf16x8, qA[ks]), sA, 0, 0, 0);
      sB = __builtin_amdgcn_mfma_f32_16x16x32_bf16(kf, __builtin_bit_cast(bf16x8, qB[ks]), sB, 0, 0, 0);
    }

    // ---- mask (keep s < t) + pack + b64 store: row lh, cols par*16+4lg.. ----
    {
      const int jl16 = jl * 16;
      const int sbase = jl16 + 4 * lg;
      const int t0A = REG * 64 + 16 * w;
      const int t0B = t0A + 32;
      const int tA = t0A + lh, tB = t0B + lh;
#pragma unroll
      for (int r = 0; r < 4; ++r) {
        if (sbase + r >= tA) sA[r] = 0.f;
        if (sbase + r >= tB) sB[r] = 0.f;
      }
      u32x2 pkA, pkB;
      pkA[0] = bf16rne(sA[0]) | (bf16rne(sA[1]) << 16);
      pkA[1] = bf16rne(sA[2]) | (bf16rne(sA[3]) << 16);
      pkB[0] = bf16rne(sB[0]) | (bf16rne(sB[1]) << 16);
      pkB[1] = bf16rne(sB[2]) | (bf16rne(sB[3]) << 16);
      char* sba = (char*)&s_lds[w * 2][0] + lh * 64 + par * 32 + lg * 8;
      char* sbb = (char*)&s_lds[w * 2 + 1][0] + lh * 64 + par * 32 + lg * 8;
      *(u32x2*)sba = pkA;
      *(u32x2*)sbb = pkB;
      if (dummy) {  // unpaired step: zero the other 16-col half
        const u32x2 z = {0u, 0u};
        *(u32x2*)((char*)&s_lds[w * 2][0] + lh * 64 + 32 + lg * 8) = z;
        *(u32x2*)((char*)&s_lds[w * 2 + 1][0] + lh * 64 + 32 + lg * 8) = z;
      }
    }

    // ---- PV over the 32-col pair ----
    if (par == 1 || dummy) {
      bf16x8 pa = *(const bf16x8*)((const char*)&s_lds[w * 2][0] + lh * 64 + lg * 16);
      bf16x8 pb = *(const bf16x8*)((const char*)&s_lds[w * 2 + 1][0] + lh * 64 + lg * 16);
#pragma unroll
      for (int df = 0; df < 8; ++df) {
        bf16x8 vf = __builtin_bit_cast(bf16x8, vfr[df]);
        oA[df] = __builtin_amdgcn_mfma_f32_16x16x32_bf16(pa, vf, oA[df], 0, 0, 0);
        oB[df] = __builtin_amdgcn_mfma_f32_16x16x32_bf16(pb, vf, oB[df], 0, 0, 0);
      }
    }

    __syncthreads();
  }

  // ---- final flush: segment 1 (block R1) ----
#pragma unroll
  for (int df = 0; df < 8; ++df) {
    int dfi = (df + 2 * jpar) & 7;
#pragma unroll
    for (int r = 0; r < 4; ++r) {
      atomicAdd(out_h + (size_t)(R1 * 64 + 16 * w + 4 * lg + r) * DV_DIM + dfi * 16 + lh, oA[dfi][r]);
      atomicAdd(out_h + (size_t)(R1 * 64 + 32 + 16 * w + 4 * lg + r) * DV_DIM + dfi * 16 + lh, oB[dfi][r]);
    }
  }
}

extern "C" void kernel_launch(void* const* d_in, const int* in_sizes, int n_in,
                              void* d_out, int out_size, void* d_ws, size_t ws_size,
                              hipStream_t stream) {
  const float* Q = (const float*)d_in[0];
  const float* V = (const float*)d_in[1];
  const float* freqs = (const float*)d_in[2];
  float* out = (float*)d_out;

  unsigned short* qr = (unsigned short*)d_ws;                        // 32 MB
  unsigned short* vtb = qr + (size_t)NH * T_DIM * N_DIM;             // 8 MB

  hipMemsetAsync(out, 0, (size_t)NH * T_DIM * DV_DIM * sizeof(float), stream);
  hipLaunchKernelGGL(rope_kernel, dim3(2048), dim3(256), 0, stream,
                     Q, freqs, (unsigned int*)qr);
  hipLaunchKernelGGL(vtrans_kernel, dim3(NH * 32 * 2), dim3(256), 0, stream, V, vtb);
  hipLaunchKernelGGL(attn_kernel, dim3(1024), dim3(128), 0, stream, qr, vtb, out);
}

// Round 4
// 160.205 us; speedup vs baseline: 1.5068x; 1.5068x over previous
//
#include <hip/hip_runtime.h>
#include <hip/hip_bf16.h>
#include <stdint.h>

#define T_DIM 2048
#define N_DIM 512
#define DV_DIM 128
#define NH 16          // B*H

typedef __bf16 bf16x8 __attribute__((ext_vector_type(8)));
typedef float f32x4 __attribute__((ext_vector_type(4)));
typedef float f32x2 __attribute__((ext_vector_type(2)));
typedef unsigned int u32x2 __attribute__((ext_vector_type(2)));
typedef unsigned int u32x4 __attribute__((ext_vector_type(4)));

__device__ __forceinline__ unsigned bf16rne(float x) {
  unsigned u = __builtin_bit_cast(unsigned, x);
  return (u + 0x7FFFu + ((u >> 16) & 1u)) >> 16;
}

__device__ __forceinline__ void load_lds16(const void* g, void* l) {
  __builtin_amdgcn_global_load_lds((const __attribute__((address_space(1))) void*)g,
                                   (__attribute__((address_space(3))) void*)l, 16, 0, 0);
}

// ---------------- RoPE: Q fp32 -> QR bf16  [bh][t][n] ----------------
__global__ void rope_kernel(const float* __restrict__ Q, const float* __restrict__ freqs,
                            unsigned int* __restrict__ qrOut) {
  const int total = NH * T_DIM * (N_DIM / 2);  // pairs
  for (int p = blockIdx.x * blockDim.x + threadIdx.x; p < total;
       p += gridDim.x * blockDim.x) {
    int n2 = p & 255;            // N/2 = 256
    int t = (p >> 8) & 2047;
    float f = freqs[2 * n2];
    f32x2 q = *(const f32x2*)(Q + 2 * (size_t)p);
    float ph = (float)t * f;
    ph = ph - floorf(ph);                 // revolutions in [0,1)
    float sn = __builtin_amdgcn_sinf(ph);
    float cn = __builtin_amdgcn_cosf(ph);
    float o0 = q.x * cn - q.y * sn;
    float o1 = q.y * cn + q.x * sn;
    qrOut[p] = bf16rne(o0) | (bf16rne(o1) << 16);
  }
}

// ---------------- V -> blocked VT bf16: vtb[bh][t/16][d][t%16] ----------------
__global__ void vtrans_kernel(const float* __restrict__ V, unsigned short* __restrict__ vtb) {
  __shared__ unsigned short tile[64][65];
  int blk = blockIdx.x;
  int bh = blk >> 6;
  int tt = (blk >> 1) & 31;  // t-tile (64 rows)
  int td = blk & 1;          // d-half (64)
  int t0 = tt * 64, d0 = td * 64;
  const float* src = V + ((size_t)bh * T_DIM + t0) * DV_DIM + d0;
  int tid = threadIdx.x;
#pragma unroll
  for (int it = 0; it < 16; ++it) {
    int sl = it * 256 + tid;
    int r = sl >> 6, c = sl & 63;   // r = t-local, c = d-local
    tile[r][c] = (unsigned short)bf16rne(src[r * DV_DIM + c]);
  }
  __syncthreads();
  int jl = tid >> 6;       // 0..3
  int dl = tid & 63;       // 0..63
  unsigned short tmp[16];
#pragma unroll
  for (int k = 0; k < 16; ++k) tmp[k] = tile[jl * 16 + k][dl];
  unsigned short* dst = vtb + (size_t)bh * (128 * DV_DIM * 16)
                        + (size_t)(tt * 4 + jl) * (DV_DIM * 16)
                        + (size_t)(d0 + dl) * 16;
  *(u32x4*)(dst) = *(u32x4*)(tmp);
  *(u32x4*)(dst + 8) = *(u32x4*)(tmp + 8);
}

// ---------------- fused masked attention ----------------
// 512 wgs x 128 thr (2 waves). wg = (head pinned to XCD via bid&7, pair ph,
// jpar). Diagonal pairing: segment0 = row-block 31-ph, segment1 = ph ->
// uniform 66 steps/wg, 2 wgs/CU, all finish together. Async pipeline:
// K triple-buf + V quad-buf staged via global_load_lds, counted
// s_waitcnt vmcnt(10) + raw s_barrier (no vmcnt(0) drain in the loop).
__global__ __launch_bounds__(128, 1)
void attn_kernel(const unsigned short* __restrict__ qr,
                 const unsigned short* __restrict__ vtb,
                 float* __restrict__ out) {
  __shared__ unsigned short k_lds[3][16 * 512];   // 48KB [buf][ks][row16][32]
  __shared__ unsigned short v_lds[4][2048];       // 16KB [buf][d128][k16]
  __shared__ unsigned short s_lds[4][16 * 32];    // 4KB  [w*2+tile][t16][s32]

  const int tid = threadIdx.x;
  const int w = tid >> 6;
  const int lane = tid & 63;
  const int lh = lane & 15;
  const int lg = lane >> 4;

  const int bid = blockIdx.x;
  const int x = bid & 7;
  const int k = bid >> 3;                 // 0..63
  const int head = x + 8 * (k & 1);       // 2 heads per XCD class
  const int jpar = (k >> 1) & 1;
  const int ph = k >> 2;                  // 0..15
  const int R0 = 31 - ph, R1 = ph;
  const int n0 = 2 * R0 + 2;              // even; total steps = 66

  const unsigned short* qr_h = qr + (size_t)head * (T_DIM * N_DIM);
  const unsigned short* vtb_h = vtb + (size_t)head * (128 * DV_DIM * 16);
  float* const out_h = out + (size_t)head * T_DIM * DV_DIM;

  u32x4 qA[16], qB[16];
  const f32x4 fzero = {0.f, 0.f, 0.f, 0.f};
  f32x4 oA[8], oB[8];

  auto loadQ = [&](int R) {
    const unsigned short* pa = qr_h + (size_t)(R * 64 + 16 * w + lh) * N_DIM + lg * 8;
    const unsigned short* pb = pa + 32 * N_DIM;
#pragma unroll
    for (int ks = 0; ks < 16; ++ks) {
      qA[ks] = *(const u32x4*)(pa + ks * 32);
      qB[ks] = *(const u32x4*)(pb + ks * 32);
    }
  };
  auto zeroO = [&]() {
#pragma unroll
    for (int d = 0; d < 8; ++d) { oA[d] = fzero; oB[d] = fzero; }
  };
  auto flushO = [&](int R) {
#pragma unroll
    for (int df = 0; df < 8; ++df) {
      int dfi = (df + 4 * jpar) & 7;      // decorrelate jpar atomic streams
#pragma unroll
      for (int r = 0; r < 4; ++r) {
        atomicAdd(out_h + (size_t)(R * 64 + 16 * w + 4 * lg + r) * DV_DIM + dfi * 16 + lh, oA[dfi][r]);
        atomicAdd(out_h + (size_t)(R * 64 + 32 + 16 * w + 4 * lg + r) * DV_DIM + dfi * 16 + lh, oB[dfi][r]);
      }
    }
  };
  // stage K block jl (16 rows x 512) + V block jl (128 d x 16) -> 10 vmcnt/wave
  auto stage = [&](int jl, int kbuf, int vbuf) {
    const char* kb = (const char*)qr_h + (size_t)jl * 16384;
#pragma unroll
    for (int it = 0; it < 8; ++it) {
      int slot = it * 128 + tid;
      int off = ((slot >> 2) & 15) * 1024 + (slot >> 6) * 64 + (slot & 3) * 16;
      load_lds16(kb + off, (char*)&k_lds[kbuf][0] + slot * 16);
    }
    const char* vb = (const char*)vtb_h + (size_t)jl * 4096;
#pragma unroll
    for (int it = 0; it < 2; ++it) {
      int slot = it * 128 + tid;
      load_lds16(vb + slot * 16, (char*)&v_lds[vbuf][0] + slot * 16);
    }
  };

  // prologue: stage blocks for t=0,1; load segment-0 Q
  stage(jpar, 0, 0);
  stage(jpar + 2, 1, 1);
  loadQ(R0);
  zeroO();

  for (int t = 0; t < 66; ++t) {
    // segment boundary: flush O for R0, reload Q for R1 (once per wg)
    if (t == n0) {
      flushO(R0);
      loadQ(R1);
      zeroO();
    }

    asm volatile("s_waitcnt vmcnt(10)" ::: "memory");  // stage(t) complete
    __builtin_amdgcn_s_barrier();                      // all waves' halves visible
    __builtin_amdgcn_sched_barrier(0);

    if (t + 2 < 66) {
      const int tn = t + 2;
      const int jln = (tn >= n0) ? (jpar + 2 * (tn - n0)) : (jpar + 2 * tn);
      stage(jln, tn % 3, tn & 3);
    }

    const int jl = (t >= n0) ? (jpar + 2 * (t - n0)) : (jpar + 2 * t);
    const int t0A = ((t >= n0) ? R1 : R0) * 64 + 16 * w;

    // ---- QK^T swapped: S'[s][t] = K·Q^T ----
    f32x4 sA = fzero, sB = fzero;
    const int kb0 = (t % 3) * 16384 + lh * 64 + lg * 16;  // bytes
#pragma unroll
    for (int ks = 0; ks < 16; ++ks) {
      bf16x8 kf = *(const bf16x8*)((const char*)k_lds + kb0 + ks * 1024);
      sA = __builtin_amdgcn_mfma_f32_16x16x32_bf16(kf, __builtin_bit_cast(bf16x8, qA[ks]), sA, 0, 0, 0);
      sB = __builtin_amdgcn_mfma_f32_16x16x32_bf16(kf, __builtin_bit_cast(bf16x8, qB[ks]), sB, 0, 0, 0);
    }

    // ---- mask (keep s < t) + pack + b64 S-store ----
    {
      const int sbase = jl * 16 + 4 * lg;
      const int tA = t0A + lh, tB = t0A + 32 + lh;
#pragma unroll
      for (int r = 0; r < 4; ++r) {
        if (sbase + r >= tA) sA[r] = 0.f;
        if (sbase + r >= tB) sB[r] = 0.f;
      }
      u32x2 pkA, pkB;
      pkA[0] = bf16rne(sA[0]) | (bf16rne(sA[1]) << 16);
      pkA[1] = bf16rne(sA[2]) | (bf16rne(sA[3]) << 16);
      pkB[0] = bf16rne(sB[0]) | (bf16rne(sB[1]) << 16);
      pkB[1] = bf16rne(sB[2]) | (bf16rne(sB[3]) << 16);
      const int par = t & 1;
      *(u32x2*)((char*)&s_lds[w * 2][0] + lh * 64 + par * 32 + lg * 8) = pkA;
      *(u32x2*)((char*)&s_lds[w * 2 + 1][0] + lh * 64 + par * 32 + lg * 8) = pkB;
    }

    // ---- PV on odd steps over the 32-col pair (jl-2, jl) ----
    if (t & 1) {
      bf16x8 pa = *(const bf16x8*)((const char*)&s_lds[w * 2][0] + lh * 64 + lg * 16);
      bf16x8 pb = *(const bf16x8*)((const char*)&s_lds[w * 2 + 1][0] + lh * 64 + lg * 16);
      const char* vAp = (const char*)&v_lds[(t + 3) & 3][0];  // block jl-2
      const char* vBp = (const char*)&v_lds[t & 3][0];        // block jl
      const char* vsel = (lg & 2) ? vBp : vAp;
#pragma unroll
      for (int df = 0; df < 8; ++df) {
        bf16x8 vf = *(const bf16x8*)(vsel + (df * 16 + lh) * 32 + (lg & 1) * 16);
        oA[df] = __builtin_amdgcn_mfma_f32_16x16x32_bf16(pa, vf, oA[df], 0, 0, 0);
        oB[df] = __builtin_amdgcn_mfma_f32_16x16x32_bf16(pb, vf, oB[df], 0, 0, 0);
      }
    }
  }

  // ---- final flush: segment 1 (block R1) ----
  flushO(R1);
}

extern "C" void kernel_launch(void* const* d_in, const int* in_sizes, int n_in,
                              void* d_out, int out_size, void* d_ws, size_t ws_size,
                              hipStream_t stream) {
  const float* Q = (const float*)d_in[0];
  const float* V = (const float*)d_in[1];
  const float* freqs = (const float*)d_in[2];
  float* out = (float*)d_out;

  unsigned short* qr = (unsigned short*)d_ws;                        // 32 MB
  unsigned short* vtb = qr + (size_t)NH * T_DIM * N_DIM;             // 8 MB

  hipMemsetAsync(out, 0, (size_t)NH * T_DIM * DV_DIM * sizeof(float), stream);
  hipLaunchKernelGGL(rope_kernel, dim3(2048), dim3(256), 0, stream,
                     Q, freqs, (unsigned int*)qr);
  hipLaunchKernelGGL(vtrans_kernel, dim3(NH * 32 * 2), dim3(256), 0, stream, V, vtb);
  hipLaunchKernelGGL(attn_kernel, dim3(512), dim3(128), 0, stream, qr, vtb, out);
}

// Round 5
// 146.831 us; speedup vs baseline: 1.6440x; 1.0911x over previous
//
#include <hip/hip_runtime.h>
#include <hip/hip_bf16.h>
#include <stdint.h>

#define T_DIM 2048
#define N_DIM 512
#define DV_DIM 128
#define NH 16          // B*H

typedef __bf16 bf16x8 __attribute__((ext_vector_type(8)));
typedef float f32x4 __attribute__((ext_vector_type(4)));
typedef float f32x2 __attribute__((ext_vector_type(2)));
typedef unsigned int u32x2 __attribute__((ext_vector_type(2)));
typedef unsigned int u32x4 __attribute__((ext_vector_type(4)));

__device__ __forceinline__ unsigned bf16rne(float x) {
  unsigned u = __builtin_bit_cast(unsigned, x);
  return (u + 0x7FFFu + ((u >> 16) & 1u)) >> 16;
}

__device__ __forceinline__ void load_lds16(const void* g, void* l) {
  __builtin_amdgcn_global_load_lds((const __attribute__((address_space(1))) void*)g,
                                   (__attribute__((address_space(3))) void*)l, 16, 0, 0);
}

// ---------------- RoPE: Q fp32 -> QR bf16  [bh][t][n] ----------------
__global__ void rope_kernel(const float* __restrict__ Q, const float* __restrict__ freqs,
                            unsigned int* __restrict__ qrOut) {
  const int total = NH * T_DIM * (N_DIM / 2);  // pairs
  for (int p = blockIdx.x * blockDim.x + threadIdx.x; p < total;
       p += gridDim.x * blockDim.x) {
    int n2 = p & 255;            // N/2 = 256
    int t = (p >> 8) & 2047;
    float f = freqs[2 * n2];
    f32x2 q = *(const f32x2*)(Q + 2 * (size_t)p);
    float ph = (float)t * f;
    ph = ph - floorf(ph);                 // revolutions in [0,1)
    float sn = __builtin_amdgcn_sinf(ph);
    float cn = __builtin_amdgcn_cosf(ph);
    float o0 = q.x * cn - q.y * sn;
    float o1 = q.y * cn + q.x * sn;
    qrOut[p] = bf16rne(o0) | (bf16rne(o1) << 16);
  }
}

// ---- V fp32 [bh][t][d] -> frag-linear bf16 blocks:
// vt32[bh][sblk32][slot j=df*64+lane][i=0..7] = V[s0+8*lg+i][16*df+lh]
__global__ void vtrans_kernel(const float* __restrict__ V, unsigned short* __restrict__ vt32) {
  __shared__ unsigned short tile[32][128];
  const int blk = blockIdx.x;
  const int bh = blk >> 6;
  const int sb = blk & 63;
  const float* src = V + ((size_t)bh * T_DIM + sb * 32) * DV_DIM;
  const int tid = threadIdx.x;
#pragma unroll
  for (int i = 0; i < 16; ++i) {
    int idx = i * 256 + tid;          // 0..4095 over [32][128]
    tile[idx >> 7][idx & 127] = (unsigned short)bf16rne(src[idx]);
  }
  __syncthreads();
  unsigned short* dst = vt32 + (size_t)blk * 4096;
#pragma unroll
  for (int jj = 0; jj < 2; ++jj) {
    int j = jj * 256 + tid;           // 0..511 slots of 8 shorts
    int df = j >> 6, ln = j & 63;
    int lh2 = ln & 15, lg2 = ln >> 4;
    unsigned short tmp[8];
#pragma unroll
    for (int i = 0; i < 8; ++i) tmp[i] = tile[8 * lg2 + i][16 * df + lh2];
    *(u32x4*)(dst + j * 8) = *(u32x4*)tmp;
  }
}

// ---------------- fused masked attention ----------------
// 1024 wgs x 256 thr (4 waves, 4 wgs/CU -> 16 waves/CU). wg = (head, pair p,
// kchunk c); all 4 kchunks of (head,p) pinned to one XCD. Wave w owns 16
// t-rows. Diagonal pairing: seg0 = block 31-p, seg1 = block p -> uniform 66
// steps of 32 s-rows. K (8KB) + V (8KB) double-buffered in FRAG-LINEAR LDS
// (every read = lane*16B, conflict-free). Output: fp32 atomicAdd (4 partials).
__global__ __launch_bounds__(256, 4)
void attn_kernel(const unsigned short* __restrict__ qr,
                 const unsigned short* __restrict__ vt32,
                 float* __restrict__ out) {
  __shared__ unsigned short k_lds[2][4096];  // [buf][frag f=st*4+ks][lane*8]
  __shared__ unsigned short v_lds[2][4096];  // [buf][frag df][lane*8]
  __shared__ unsigned short s_lds[2048];     // [wave][A-frag-linear 512]

  const int tid = threadIdx.x;
  const int w = tid >> 6;
  const int lane = tid & 63;
  const int lh = lane & 15;
  const int lg = lane >> 4;

  const int bid = blockIdx.x;
  const int x = bid & 7;
  const int r_ = bid >> 3;
  const int c = r_ & 3;                    // kchunk
  const int u = r_ >> 2;                   // 0..31
  const int h = u & 15;
  const int p = ((x - h) & 7) + ((u >> 4) << 3);
  const int R0 = 31 - p, R1 = p;
  const int n0 = 2 * R0 + 2;               // steps in segment 0; total 66

  const unsigned short* qr_h = qr + (size_t)h * (T_DIM * N_DIM);
  const unsigned short* vt_h = vt32 + (size_t)h * (64 * 4096);
  float* const out_h = out + (size_t)h * T_DIM * DV_DIM;

  // staging source offsets (bytes), 2 K-slots + 2 V-slots per thread
  int koff[2];
#pragma unroll
  for (int it = 0; it < 2; ++it) {
    int j = it * 256 + tid;                // 0..511
    int f = j >> 6, ln = j & 63;
    int st = f >> 2, ks = f & 3;
    koff[it] = (st * 16 + (ln & 15)) * 1024 + c * 256 + ks * 64 + (ln >> 4) * 16;
  }

  u32x4 q[4];
  const f32x4 fzero = {0.f, 0.f, 0.f, 0.f};
  f32x4 o[8];

  auto loadQ = [&](int R) {
    const unsigned short* pq = qr_h + (size_t)(R * 64 + 16 * w + lh) * N_DIM + c * 128 + lg * 8;
#pragma unroll
    for (int ks = 0; ks < 4; ++ks) q[ks] = *(const u32x4*)(pq + ks * 32);
  };
  auto zeroO = [&]() {
#pragma unroll
    for (int d = 0; d < 8; ++d) o[d] = fzero;
  };
  auto flushO = [&](int R) {
    const int tb = R * 64 + 16 * w;
#pragma unroll
    for (int df = 0; df < 8; ++df)
#pragma unroll
      for (int r = 0; r < 4; ++r)
        atomicAdd(out_h + (size_t)(tb + 4 * lg + r) * DV_DIM + df * 16 + lh, o[df][r]);
  };
  auto stage = [&](int sblk, int buf) {
    const char* kb = (const char*)qr_h + (size_t)sblk * 32 * 1024;
#pragma unroll
    for (int it = 0; it < 2; ++it)
      load_lds16(kb + koff[it], (char*)&k_lds[buf][0] + (it * 256 + tid) * 16);
    const char* vb = (const char*)vt_h + (size_t)sblk * 8192;
#pragma unroll
    for (int it = 0; it < 2; ++it)
      load_lds16(vb + (it * 256 + tid) * 16, (char*)&v_lds[buf][0] + (it * 256 + tid) * 16);
  };

  loadQ(R0);
  zeroO();
  stage(0, 0);
  __syncthreads();

  for (int t = 0; t < 66; ++t) {
    if (t == n0) {          // segment switch: emit block R0, start block R1
      flushO(R0);
      loadQ(R1);
      zeroO();
    }
    const int buf = t & 1;
    if (t + 1 < 66) {
      const int tn = t + 1;
      stage((tn >= n0) ? (tn - n0) : tn, buf ^ 1);
    }
    const int sblk = (t >= n0) ? (t - n0) : t;
    const int tb = ((t >= n0) ? R1 : R0) * 64 + 16 * w;
    const int s0 = sblk * 32;

    if (s0 < tb + 16) {     // wave has at least one unmasked element
      // ---- QK^T swapped: S'[s][t] = K·Q^T over this wg's 128-k chunk ----
      f32x4 sS0 = fzero, sS1 = fzero;
#pragma unroll
      for (int ks = 0; ks < 4; ++ks) {
        bf16x8 kf0 = *(const bf16x8*)&k_lds[buf][(ks)*512 + lane * 8];
        bf16x8 kf1 = *(const bf16x8*)&k_lds[buf][(4 + ks) * 512 + lane * 8];
        bf16x8 qk = __builtin_bit_cast(bf16x8, q[ks]);
        sS0 = __builtin_amdgcn_mfma_f32_16x16x32_bf16(kf0, qk, sS0, 0, 0, 0);
        sS1 = __builtin_amdgcn_mfma_f32_16x16x32_bf16(kf1, qk, sS1, 0, 0, 0);
      }
      // ---- strict causal mask (keep s < t) ----
      if (s0 + 32 > tb) {
        const int tg = tb + lh;
#pragma unroll
        for (int r = 0; r < 4; ++r) {
          if (s0 + 4 * lg + r >= tg) sS0[r] = 0.f;
          if (s0 + 16 + 4 * lg + r >= tg) sS1[r] = 0.f;
        }
      }
      // ---- pack to bf16, store in A-frag-linear order ----
      {
        u32x2 pk0, pk1;
        pk0[0] = bf16rne(sS0[0]) | (bf16rne(sS0[1]) << 16);
        pk0[1] = bf16rne(sS0[2]) | (bf16rne(sS0[3]) << 16);
        pk1[0] = bf16rne(sS1[0]) | (bf16rne(sS1[1]) << 16);
        pk1[1] = bf16rne(sS1[2]) | (bf16rne(sS1[3]) << 16);
        const int sb = w * 512 + lh * 8 + (lg >> 1) * 128 + (lg & 1) * 4;
        *(u32x2*)&s_lds[sb] = pk0;          // st = 0
        *(u32x2*)&s_lds[sb + 256] = pk1;    // st = 1
      }
      // ---- PV: O += P·V  (K = 32 s-rows, all frag reads lane-linear) ----
      {
        bf16x8 pa = *(const bf16x8*)&s_lds[w * 512 + lane * 8];
#pragma unroll
        for (int df = 0; df < 8; ++df) {
          bf16x8 vf = *(const bf16x8*)&v_lds[buf][df * 512 + lane * 8];
          o[df] = __builtin_amdgcn_mfma_f32_16x16x32_bf16(pa, vf, o[df], 0, 0, 0);
        }
      }
    }
    __syncthreads();   // stage(t+1) landed; buf free for overwrite next step
  }

  flushO(R1);
}

extern "C" void kernel_launch(void* const* d_in, const int* in_sizes, int n_in,
                              void* d_out, int out_size, void* d_ws, size_t ws_size,
                              hipStream_t stream) {
  const float* Q = (const float*)d_in[0];
  const float* V = (const float*)d_in[1];
  const float* freqs = (const float*)d_in[2];
  float* out = (float*)d_out;

  unsigned short* qr = (unsigned short*)d_ws;                        // 32 MB
  unsigned short* vt = qr + (size_t)NH * T_DIM * N_DIM;              // 8 MB

  hipMemsetAsync(out, 0, (size_t)NH * T_DIM * DV_DIM * sizeof(float), stream);
  hipLaunchKernelGGL(rope_kernel, dim3(2048), dim3(256), 0, stream,
                     Q, freqs, (unsigned int*)qr);
  hipLaunchKernelGGL(vtrans_kernel, dim3(NH * 64), dim3(256), 0, stream, V, vt);
  hipLaunchKernelGGL(attn_kernel, dim3(1024), dim3(256), 0, stream, qr, vt, out);
}

// Round 6
// 145.702 us; speedup vs baseline: 1.6567x; 1.0077x over previous
//
#include <hip/hip_runtime.h>
#include <hip/hip_bf16.h>
#include <stdint.h>

#define T_DIM 2048
#define N_DIM 512
#define DV_DIM 128
#define NH 16          // B*H

typedef __bf16 bf16x8 __attribute__((ext_vector_type(8)));
typedef float f32x4 __attribute__((ext_vector_type(4)));
typedef float f32x2 __attribute__((ext_vector_type(2)));
typedef unsigned int u32x2 __attribute__((ext_vector_type(2)));
typedef unsigned int u32x4 __attribute__((ext_vector_type(4)));

__device__ __forceinline__ unsigned bf16rne(float x) {
  unsigned u = __builtin_bit_cast(unsigned, x);
  return (u + 0x7FFFu + ((u >> 16) & 1u)) >> 16;
}

__device__ __forceinline__ void load_lds16(const void* g, void* l) {
  __builtin_amdgcn_global_load_lds((const __attribute__((address_space(1))) void*)g,
                                   (__attribute__((address_space(3))) void*)l, 16, 0, 0);
}

// ---------------- RoPE: Q fp32 -> QR bf16  [bh][t][n] ----------------
__global__ void rope_kernel(const float* __restrict__ Q, const float* __restrict__ freqs,
                            unsigned int* __restrict__ qrOut) {
  const int total = NH * T_DIM * (N_DIM / 2);  // pairs
  for (int p = blockIdx.x * blockDim.x + threadIdx.x; p < total;
       p += gridDim.x * blockDim.x) {
    int n2 = p & 255;            // N/2 = 256
    int t = (p >> 8) & 2047;
    float f = freqs[2 * n2];
    f32x2 q = *(const f32x2*)(Q + 2 * (size_t)p);
    float ph = (float)t * f;
    ph = ph - floorf(ph);                 // revolutions in [0,1)
    float sn = __builtin_amdgcn_sinf(ph);
    float cn = __builtin_amdgcn_cosf(ph);
    float o0 = q.x * cn - q.y * sn;
    float o1 = q.y * cn + q.x * sn;
    qrOut[p] = bf16rne(o0) | (bf16rne(o1) << 16);
  }
}

// ---- V fp32 [bh][t][d] -> frag-linear bf16 blocks:
// vt32[bh][sblk32][slot j=df*64+lane][i=0..7] = V[s0+8*lg+i][16*df+lh]
__global__ void vtrans_kernel(const float* __restrict__ V, unsigned short* __restrict__ vt32) {
  __shared__ unsigned short tile[32][128];
  const int blk = blockIdx.x;
  const int bh = blk >> 6;
  const int sb = blk & 63;
  const float* src = V + ((size_t)bh * T_DIM + sb * 32) * DV_DIM;
  const int tid = threadIdx.x;
#pragma unroll
  for (int i = 0; i < 16; ++i) {
    int idx = i * 256 + tid;          // 0..4095 over [32][128]
    tile[idx >> 7][idx & 127] = (unsigned short)bf16rne(src[idx]);
  }
  __syncthreads();
  unsigned short* dst = vt32 + (size_t)blk * 4096;
#pragma unroll
  for (int jj = 0; jj < 2; ++jj) {
    int j = jj * 256 + tid;           // 0..511 slots of 8 shorts
    int df = j >> 6, ln = j & 63;
    int lh2 = ln & 15, lg2 = ln >> 4;
    unsigned short tmp[8];
#pragma unroll
    for (int i = 0; i < 8; ++i) tmp[i] = tile[8 * lg2 + i][16 * df + lh2];
    *(u32x4*)(dst + j * 8) = *(u32x4*)tmp;
  }
}

// ---------------- fused masked attention ----------------
// 1024 wgs x 256 thr (4 waves, 4 wgs/CU -> 16 waves/CU). wg = (head, pair p,
// kchunk c); all 4 kchunks of (head,p) pinned to one XCD. Diagonal pairing
// with REVERSED segment 1 (sblk = 65-t) so all wgs of a head touch the same
// two s-blocks at every step -> L2-aligned. Counted-vmcnt 2-barrier pipeline:
// stage(t+1) issued at top, s_waitcnt vmcnt(4) waits only stage(t); no full
// drain in the loop. K/V double-buffered in frag-linear LDS (reads lane*16B,
// conflict-free). Output: fp32 atomicAdd partials (4 kchunks).
__global__ __launch_bounds__(256, 4)
void attn_kernel(const unsigned short* __restrict__ qr,
                 const unsigned short* __restrict__ vt32,
                 float* __restrict__ out) {
  __shared__ unsigned short k_lds[2][4096];  // [buf][frag f=st*4+ks][lane*8]
  __shared__ unsigned short v_lds[2][4096];  // [buf][frag df][lane*8]
  __shared__ unsigned short s_lds[2048];     // [wave][A-frag-linear 512]

  const int tid = threadIdx.x;
  const int w = tid >> 6;
  const int lane = tid & 63;
  const int lh = lane & 15;
  const int lg = lane >> 4;

  const int bid = blockIdx.x;
  const int x = bid & 7;
  const int r_ = bid >> 3;
  const int c = r_ & 3;                    // kchunk
  const int u = r_ >> 2;                   // 0..31
  const int h = u & 15;
  const int p = ((x - h) & 7) + ((u >> 4) << 3);
  const int R0 = 31 - p, R1 = p;
  const int n0 = 2 * R0 + 2;               // steps in segment 0; total 66

  const unsigned short* qr_h = qr + (size_t)h * (T_DIM * N_DIM);
  const unsigned short* vt_h = vt32 + (size_t)h * (64 * 4096);
  float* const out_h = out + (size_t)h * T_DIM * DV_DIM;

  // staging source offsets (bytes), 2 K-slots + 2 V-slots per thread
  int koff[2];
#pragma unroll
  for (int it = 0; it < 2; ++it) {
    int j = it * 256 + tid;                // 0..511
    int f = j >> 6, ln = j & 63;
    int st = f >> 2, ks = f & 3;
    koff[it] = (st * 16 + (ln & 15)) * 1024 + c * 256 + ks * 64 + (ln >> 4) * 16;
  }

  u32x4 q[4];
  const f32x4 fzero = {0.f, 0.f, 0.f, 0.f};
  f32x4 o[8];

  auto loadQ = [&](int R) {
    const unsigned short* pq = qr_h + (size_t)(R * 64 + 16 * w + lh) * N_DIM + c * 128 + lg * 8;
#pragma unroll
    for (int ks = 0; ks < 4; ++ks) q[ks] = *(const u32x4*)(pq + ks * 32);
  };
  auto zeroO = [&]() {
#pragma unroll
    for (int d = 0; d < 8; ++d) o[d] = fzero;
  };
  auto flushO = [&](int R) {
    const int tb = R * 64 + 16 * w;
#pragma unroll
    for (int df = 0; df < 8; ++df)
#pragma unroll
      for (int r = 0; r < 4; ++r)
        atomicAdd(out_h + (size_t)(tb + 4 * lg + r) * DV_DIM + df * 16 + lh, o[df][r]);
  };
  // 4 global_load_lds per thread per stage (2 K + 2 V) -> vmcnt unit = 4
  auto stage = [&](int sblk, int buf) {
    const char* kb = (const char*)qr_h + (size_t)sblk * 32 * 1024;
#pragma unroll
    for (int it = 0; it < 2; ++it)
      load_lds16(kb + koff[it], (char*)&k_lds[buf][0] + (it * 256 + tid) * 16);
    const char* vb = (const char*)vt_h + (size_t)sblk * 8192;
#pragma unroll
    for (int it = 0; it < 2; ++it)
      load_lds16(vb + (it * 256 + tid) * 16, (char*)&v_lds[buf][0] + (it * 256 + tid) * 16);
  };

  stage(0, 0);
  loadQ(R0);
  zeroO();

  for (int t = 0; t < 66; ++t) {
    if (t == n0) {          // segment switch: emit block R0, start block R1
      flushO(R0);
      loadQ(R1);
      zeroO();
    }
    const int buf = t & 1;
    // issue next stage, then wait ONLY for stage(t) (the 4 newest stay in flight)
    if (t + 1 < 66) {
      const int tn = t + 1;
      stage((tn < n0) ? tn : (65 - tn), buf ^ 1);
      asm volatile("s_waitcnt vmcnt(4)" ::: "memory");
    } else {
      asm volatile("s_waitcnt vmcnt(0)" ::: "memory");
    }
    __builtin_amdgcn_s_barrier();          // all waves' stage(t) halves visible
    __builtin_amdgcn_sched_barrier(0);

    const int sblk = (t < n0) ? t : (65 - t);
    const int tb = ((t >= n0) ? R1 : R0) * 64 + 16 * w;
    const int s0 = sblk * 32;

    if (s0 < tb + 16) {     // wave has at least one unmasked element
      // ---- QK^T swapped: S'[s][t] = K·Q^T over this wg's 128-k chunk ----
      f32x4 sS0 = fzero, sS1 = fzero;
#pragma unroll
      for (int ks = 0; ks < 4; ++ks) {
        bf16x8 kf0 = *(const bf16x8*)&k_lds[buf][(ks)*512 + lane * 8];
        bf16x8 kf1 = *(const bf16x8*)&k_lds[buf][(4 + ks) * 512 + lane * 8];
        bf16x8 qk = __builtin_bit_cast(bf16x8, q[ks]);
        sS0 = __builtin_amdgcn_mfma_f32_16x16x32_bf16(kf0, qk, sS0, 0, 0, 0);
        sS1 = __builtin_amdgcn_mfma_f32_16x16x32_bf16(kf1, qk, sS1, 0, 0, 0);
      }
      // ---- strict causal mask (keep s < t) ----
      if (s0 + 32 > tb) {
        const int tg = tb + lh;
#pragma unroll
        for (int r = 0; r < 4; ++r) {
          if (s0 + 4 * lg + r >= tg) sS0[r] = 0.f;
          if (s0 + 16 + 4 * lg + r >= tg) sS1[r] = 0.f;
        }
      }
      // ---- pack to bf16, store in A-frag-linear order ----
      {
        u32x2 pk0, pk1;
        pk0[0] = bf16rne(sS0[0]) | (bf16rne(sS0[1]) << 16);
        pk0[1] = bf16rne(sS0[2]) | (bf16rne(sS0[3]) << 16);
        pk1[0] = bf16rne(sS1[0]) | (bf16rne(sS1[1]) << 16);
        pk1[1] = bf16rne(sS1[2]) | (bf16rne(sS1[3]) << 16);
        const int sb = w * 512 + lh * 8 + (lg >> 1) * 128 + (lg & 1) * 4;
        *(u32x2*)&s_lds[sb] = pk0;          // st = 0
        *(u32x2*)&s_lds[sb + 256] = pk1;    // st = 1
      }
      // ---- PV: O += P·V  (K = 32 s-rows, all frag reads lane-linear) ----
      {
        bf16x8 pa = *(const bf16x8*)&s_lds[w * 512 + lane * 8];
#pragma unroll
        for (int df = 0; df < 8; ++df) {
          bf16x8 vf = *(const bf16x8*)&v_lds[buf][df * 512 + lane * 8];
          o[df] = __builtin_amdgcn_mfma_f32_16x16x32_bf16(pa, vf, o[df], 0, 0, 0);
        }
      }
    }
    // ds_reads of buf complete before anyone overwrites it next step
    asm volatile("s_waitcnt lgkmcnt(0)" ::: "memory");
    __builtin_amdgcn_sched_barrier(0);
    __builtin_amdgcn_s_barrier();
  }

  flushO(R1);
}

extern "C" void kernel_launch(void* const* d_in, const int* in_sizes, int n_in,
                              void* d_out, int out_size, void* d_ws, size_t ws_size,
                              hipStream_t stream) {
  const float* Q = (const float*)d_in[0];
  const float* V = (const float*)d_in[1];
  const float* freqs = (const float*)d_in[2];
  float* out = (float*)d_out;

  unsigned short* qr = (unsigned short*)d_ws;                        // 32 MB
  unsigned short* vt = qr + (size_t)NH * T_DIM * N_DIM;              // 8 MB

  hipMemsetAsync(out, 0, (size_t)NH * T_DIM * DV_DIM * sizeof(float), stream);
  hipLaunchKernelGGL(rope_kernel, dim3(2048), dim3(256), 0, stream,
                     Q, freqs, (unsigned int*)qr);
  hipLaunchKernelGGL(vtrans_kernel, dim3(NH * 64), dim3(256), 0, stream, V, vt);
  hipLaunchKernelGGL(attn_kernel, dim3(1024), dim3(256), 0, stream, qr, vt, out);
}